// Round 9
// baseline (362.498 us; speedup 1.0000x reference)
//
#include <hip/hip_runtime.h>
#include <hip/hip_bf16.h>
#include <math.h>

using bf16 = __hip_bfloat16;
typedef __attribute__((ext_vector_type(8))) short short8;
typedef __attribute__((ext_vector_type(4))) float float4v;
typedef __attribute__((ext_vector_type(4))) unsigned short ushort4v;

#define DEVI __device__ __forceinline__

constexpr int Nc = 98;
constexpr int NWIN = 256;
constexpr int BNc = 4 * NWIN;           // 1024 windows
constexpr int NTOK = 4 * 8 * 56 * 56;   // 100352 tokens

DEVI float b2f(bf16 v) { return __bfloat162float(v); }
DEVI short f2bs(float v) { bf16 h = __float2bfloat16(v); return *reinterpret_cast<short*>(&h); }

DEVI float4v mfma16(short8 a, short8 b, float4v c) {
    return __builtin_amdgcn_mfma_f32_16x16x32_bf16(a, b, c, 0, 0, 0);
}

// ---------------- K0a: weights fp32 -> bf16 (qkv|proj|fc1|fc2 packed) ----------------
__global__ __launch_bounds__(256) void k_wconv(const float* __restrict__ qw, const float* __restrict__ pw,
                                               const float* __restrict__ f1, const float* __restrict__ f2,
                                               short* __restrict__ wbf) {
    int i = blockIdx.x * 256 + threadIdx.x;           // 196608 total
    float v;
    if (i < 49152) v = qw[i];
    else if (i < 65536) v = pw[i - 49152];
    else if (i < 131072) v = f1[i - 65536];
    else v = f2[i - 131072];
    wbf[i] = f2bs(v);
}

// ---------------- K0b: combined bias+mask table, transposed ----------------
__global__ __launch_bounds__(256) void k_cmb(const int* __restrict__ relidx, const float* __restrict__ rpb,
                                             const float* __restrict__ mask, short* __restrict__ cmbT) {
    int elem = blockIdx.x * 256 + threadIdx.x;        // [0,12544)
    int sl = blockIdx.y;                              // wc*4+head
    int wc = sl >> 2, head = sl & 3;
    int j = elem / 112, i = elem - j * 112;
    float v;
    if (j >= 98)      v = -1e30f;
    else if (i >= 98) v = 0.f;
    else              v = rpb[relidx[i * 98 + j] * 4 + head] + mask[(size_t)wc * 9604 + i * 98 + j];
    cmbT[(size_t)sl * 12544 + elem] = f2bs(v);
}

// ---------------- K1: LN1 + cyclic shift + window partition ----------------
__global__ __launch_bounds__(256) void k_ln1_win(const float* __restrict__ x,
                                                 const float* __restrict__ g,
                                                 const float* __restrict__ bta,
                                                 bf16* __restrict__ xw) {
    int wave = (blockIdx.x * 256 + threadIdx.x) >> 6;
    int lane = threadIdx.x & 63;
    int win = wave / Nc, n = wave % Nc;
    int bb = win >> 8;
    int rem = win & 255;
    int dblk = rem >> 6, hblk = (rem >> 3) & 7, wblk = rem & 7;
    int wd = n / 49, r49 = n % 49, wh = r49 / 7, ww = r49 % 7;
    int d = dblk * 2 + wd, h = hblk * 7 + wh, w = wblk * 7 + ww;
    int ds = d + 1;  if (ds >= 8)  ds -= 8;
    int hs = h + 3;  if (hs >= 56) hs -= 56;
    int wsp = w + 3; if (wsp >= 56) wsp -= 56;
    size_t src = ((((size_t)bb * 8 + ds) * 56 + hs) * 56 + wsp) * 128;
    int c = lane * 2;
    float2 v = *reinterpret_cast<const float2*>(x + src + c);
    float v0 = v.x, v1 = v.y;
    float s = v0 + v1, sq = v0 * v0 + v1 * v1;
    #pragma unroll
    for (int off = 32; off; off >>= 1) { s += __shfl_xor(s, off); sq += __shfl_xor(sq, off); }
    float mean = s * (1.0f / 128.0f);
    float var  = sq * (1.0f / 128.0f) - mean * mean;
    float inv  = rsqrtf(var + 1e-5f);
    size_t dst = (size_t)wave * 128 + c;
    xw[dst]     = __float2bfloat16((v0 - mean) * inv * g[c]     + bta[c]);
    xw[dst + 1] = __float2bfloat16((v1 - mean) * inv * g[c + 1] + bta[c + 1]);
}

// ---------------- MFMA GEMM (qkv / proj): out = A @ W^T + bias, bf16 out ----------------
template<int K, int EPI>
__global__ __launch_bounds__(256) void k_gemm_mfma(const short* __restrict__ A,
                                                   const short* __restrict__ Bw,
                                                   const float* __restrict__ bias,
                                                   bf16* __restrict__ out, int Ncols) {
    __shared__ __align__(16) short smem[128 * 136];   // staging (2x8192) U bf16-epilogue (17408)
    short* sA = smem;
    short* sB = smem + 8192;
    int t = threadIdx.x;
    int lane = t & 63, wid = t >> 6;
    int wm = wid >> 1, wn = wid & 1;
    int m0 = blockIdx.x * 128, n0 = blockIdx.y * 128;
    float4v acc[4][4];
    #pragma unroll
    for (int a = 0; a < 4; ++a)
        #pragma unroll
        for (int b = 0; b < 4; ++b) acc[a][b] = (float4v){0.f, 0.f, 0.f, 0.f};

    for (int k0 = 0; k0 < K; k0 += 64) {
        #pragma unroll
        for (int v = 0; v < 4; ++v) {
            int vid = t + v * 256;
            int row = vid >> 3, ch = vid & 7;
            int chs = ch ^ (row & 7);
            uint4 ua = *reinterpret_cast<const uint4*>(A + (size_t)(m0 + row) * K + k0 + ch * 8);
            *reinterpret_cast<uint4*>(&sA[row * 64 + chs * 8]) = ua;
            uint4 ub = *reinterpret_cast<const uint4*>(Bw + (size_t)(n0 + row) * K + k0 + ch * 8);
            *reinterpret_cast<uint4*>(&sB[row * 64 + chs * 8]) = ub;
        }
        __syncthreads();
        #pragma unroll
        for (int kk = 0; kk < 2; ++kk) {
            int crb = kk * 4 + (lane >> 4);
            short8 af[4], bfr[4];
            #pragma unroll
            for (int mf = 0; mf < 4; ++mf) {
                int row = wm * 64 + mf * 16 + (lane & 15);
                af[mf] = *reinterpret_cast<const short8*>(&sA[row * 64 + (crb ^ (row & 7)) * 8]);
            }
            #pragma unroll
            for (int nf = 0; nf < 4; ++nf) {
                int row = wn * 64 + nf * 16 + (lane & 15);
                bfr[nf] = *reinterpret_cast<const short8*>(&sB[row * 64 + (crb ^ (row & 7)) * 8]);
            }
            #pragma unroll
            for (int mf = 0; mf < 4; ++mf)
                #pragma unroll
                for (int nf = 0; nf < 4; ++nf)
                    acc[mf][nf] = mfma16(af[mf], bfr[nf], acc[mf][nf]);
        }
        __syncthreads();
    }
    // ---- bf16 epilogue: acc -> LDS [128][136] -> 16B global stores ----
    #pragma unroll
    for (int nf = 0; nf < 4; ++nf) {
        int col = wn * 64 + nf * 16 + (lane & 15);
        int gcol = n0 + col;
        float bv = bias[gcol];
        #pragma unroll
        for (int mf = 0; mf < 4; ++mf) {
            #pragma unroll
            for (int r = 0; r < 4; ++r) {
                int row = wm * 64 + mf * 16 + (lane >> 4) * 4 + r;
                float v = acc[mf][nf][r] + bv;
                if (EPI == 0) { if (gcol < 128) v *= 0.17677669529663689f; }
                smem[row * 136 + col] = f2bs(v);
            }
        }
    }
    __syncthreads();
    #pragma unroll
    for (int p = 0; p < 8; ++p) {
        int row = p * 16 + (t >> 4);
        int c0 = (t & 15) * 8;
        uint4 val = *reinterpret_cast<const uint4*>(&smem[row * 136 + c0]);
        *reinterpret_cast<uint4*>(out + (size_t)(m0 + row) * Ncols + n0 + c0) = val;
    }
}

// ---------------- K3: MFMA window attention ----------------
__global__ __launch_bounds__(256, 4) void k_attn_mfma(const bf16* __restrict__ qkv,
                                                      const short* __restrict__ cmbT,
                                                      bf16* __restrict__ aout) {
    constexpr int QP = 40;
    constexpr int VP = 136;
    constexpr int PP = 136;
    __shared__ __align__(16) char smem[8704 + 30464];
    short* sVT = (short*)smem;                     // [32][136]
    short* sQ  = (short*)(smem + 8704);            // [112][40]
    short* sK  = (short*)(smem + 8704 + 8960);     // [112][40]
    short* sP  = (short*)(smem + 8704);            // [112][136]  (aliases sQ/sK)
    int t = threadIdx.x, lane = t & 63, wid = t >> 6;
    int win = blockIdx.x >> 2, head = blockIdx.x & 3;
    const bf16* base = qkv + (size_t)win * Nc * 384 + head * 32;

    for (int idx = t; idx < Nc * 4; idx += 256) {
        int i = idx >> 2, g = idx & 3;
        uint4 q4 = *reinterpret_cast<const uint4*>(base + (size_t)i * 384 + g * 8);
        uint4 k4 = *reinterpret_cast<const uint4*>(base + (size_t)i * 384 + 128 + g * 8);
        uint4 v4 = *reinterpret_cast<const uint4*>(base + (size_t)i * 384 + 256 + g * 8);
        *reinterpret_cast<uint4*>(&sQ[i * QP + g * 8]) = q4;
        *reinterpret_cast<uint4*>(&sK[i * QP + g * 8]) = k4;
        const short* vp = reinterpret_cast<const short*>(&v4);
        #pragma unroll
        for (int e = 0; e < 8; ++e) sVT[(g * 8 + e) * VP + i] = vp[e];
    }
    for (int idx = t; idx < 14 * QP; idx += 256) {
        int r = 98 + idx / QP, c = idx % QP;
        sQ[r * QP + c] = 0; sK[r * QP + c] = 0;
    }
    for (int idx = t; idx < 32 * 30; idx += 256) {
        int d = idx / 30, c = 98 + idx % 30;
        sVT[d * VP + c] = 0;
    }
    __syncthreads();

    float4v s[2][7];
    #pragma unroll
    for (int mi = 0; mi < 2; ++mi)
        #pragma unroll
        for (int fn = 0; fn < 7; ++fn) s[mi][fn] = (float4v){0.f, 0.f, 0.f, 0.f};
    short8 qf[2];
    #pragma unroll
    for (int mi = 0; mi < 2; ++mi) {
        if (wid * 2 + mi < 7) {
            int row = (wid * 2 + mi) * 16 + (lane & 15);
            qf[mi] = *reinterpret_cast<const short8*>(&sQ[row * QP + (lane >> 4) * 8]);
        }
    }
    #pragma unroll
    for (int fn = 0; fn < 7; ++fn) {
        short8 kf = *reinterpret_cast<const short8*>(&sK[(fn * 16 + (lane & 15)) * QP + (lane >> 4) * 8]);
        #pragma unroll
        for (int mi = 0; mi < 2; ++mi) {
            if (wid * 2 + mi < 7) s[mi][fn] = mfma16(qf[mi], kf, s[mi][fn]);
        }
    }

    const unsigned short* cb = (const unsigned short*)(cmbT + (size_t)((win & 255) * 4 + head) * 12544);
    #pragma unroll
    for (int mi = 0; mi < 2; ++mi) {
        if (wid * 2 + mi >= 7) continue;
        int i0 = (wid * 2 + mi) * 16 + (lane >> 4) * 4;
        #pragma unroll
        for (int fn = 0; fn < 7; ++fn) {
            int j = fn * 16 + (lane & 15);
            ushort4v bm4 = *reinterpret_cast<const ushort4v*>(cb + j * 112 + i0);
            #pragma unroll
            for (int r = 0; r < 4; ++r) {
                union { unsigned u; float f; } cv; cv.u = ((unsigned)bm4[r]) << 16;
                s[mi][fn][r] = __expf(s[mi][fn][r] + cv.f);
            }
        }
        #pragma unroll
        for (int r = 0; r < 4; ++r) {
            float sum = 0.f;
            #pragma unroll
            for (int fn = 0; fn < 7; ++fn) sum += s[mi][fn][r];
            #pragma unroll
            for (int m = 1; m <= 8; m <<= 1) sum += __shfl_xor(sum, m);
            float inv = 1.0f / sum;
            #pragma unroll
            for (int fn = 0; fn < 7; ++fn) s[mi][fn][r] *= inv;
        }
    }
    __syncthreads();

    for (int idx = t; idx < 112 * 16; idx += 256) {
        int rr = idx >> 4, c2 = 112 + (idx & 15);
        sP[rr * PP + c2] = 0;
    }
    #pragma unroll
    for (int mi = 0; mi < 2; ++mi) {
        if (wid * 2 + mi >= 7) continue;
        int i0 = (wid * 2 + mi) * 16 + (lane >> 4) * 4;
        #pragma unroll
        for (int r = 0; r < 4; ++r) {
            #pragma unroll
            for (int fn = 0; fn < 7; ++fn) {
                int j = fn * 16 + (lane & 15);
                sP[(i0 + r) * PP + j] = f2bs(s[mi][fn][r]);
            }
        }
    }
    __syncthreads();

    float4v o[2][2];
    #pragma unroll
    for (int mi = 0; mi < 2; ++mi)
        #pragma unroll
        for (int nd = 0; nd < 2; ++nd) o[mi][nd] = (float4v){0.f, 0.f, 0.f, 0.f};
    #pragma unroll
    for (int jc = 0; jc < 4; ++jc) {
        short8 pf[2];
        #pragma unroll
        for (int mi = 0; mi < 2; ++mi) {
            if (wid * 2 + mi < 7) {
                int row = (wid * 2 + mi) * 16 + (lane & 15);
                pf[mi] = *reinterpret_cast<const short8*>(&sP[row * PP + jc * 32 + (lane >> 4) * 8]);
            }
        }
        #pragma unroll
        for (int nd = 0; nd < 2; ++nd) {
            short8 vf = *reinterpret_cast<const short8*>(&sVT[(nd * 16 + (lane & 15)) * VP + jc * 32 + (lane >> 4) * 8]);
            #pragma unroll
            for (int mi = 0; mi < 2; ++mi) {
                if (wid * 2 + mi < 7) o[mi][nd] = mfma16(pf[mi], vf, o[mi][nd]);
            }
        }
    }
    bf16* obase = aout + (size_t)win * Nc * 128 + head * 32;
    #pragma unroll
    for (int mi = 0; mi < 2; ++mi) {
        if (wid * 2 + mi >= 7) continue;
        #pragma unroll
        for (int nd = 0; nd < 2; ++nd) {
            int d = nd * 16 + (lane & 15);
            #pragma unroll
            for (int r = 0; r < 4; ++r) {
                int i = (wid * 2 + mi) * 16 + (lane >> 4) * 4 + r;
                if (i < 98) obase[(size_t)i * 128 + d] = __float2bfloat16(o[mi][nd][r]);
            }
        }
    }
}

// ---------------- K5: window reverse + residual + LN2 fused ----------------
__global__ __launch_bounds__(256) void k_resid_ln2(const float* __restrict__ x,
                                                   const bf16* __restrict__ pt,
                                                   const float* __restrict__ g,
                                                   const float* __restrict__ bta,
                                                   float* __restrict__ x1,
                                                   bf16* __restrict__ xn2) {
    int tok = (blockIdx.x * 256 + threadIdx.x) >> 6;
    int lane = threadIdx.x & 63;
    int ww = tok % 56; int t2 = tok / 56;
    int hh = t2 % 56;  int t3 = t2 / 56;
    int dd = t3 & 7;   int bb = t3 >> 3;
    int d = dd + 7;  if (d >= 8)  d -= 8;
    int h = hh + 53; if (h >= 56) h -= 56;
    int w = ww + 53; if (w >= 56) w -= 56;
    int win = ((bb * 4 + (d >> 1)) * 8 + h / 7) * 8 + w / 7;
    int n = (d & 1) * 49 + (h % 7) * 7 + (w % 7);
    int c = lane * 2;
    const bf16* pp = pt + ((size_t)win * Nc + n) * 128 + c;
    float2 xv = *reinterpret_cast<const float2*>(x + (size_t)tok * 128 + c);
    float v0 = xv.x + b2f(pp[0]);
    float v1 = xv.y + b2f(pp[1]);
    *reinterpret_cast<float2*>(x1 + (size_t)tok * 128 + c) = float2{v0, v1};
    float s = v0 + v1, sq = v0 * v0 + v1 * v1;
    #pragma unroll
    for (int off = 32; off; off >>= 1) { s += __shfl_xor(s, off); sq += __shfl_xor(sq, off); }
    float mean = s * (1.0f / 128.0f);
    float var  = sq * (1.0f / 128.0f) - mean * mean;
    float inv  = rsqrtf(var + 1e-5f);
    xn2[(size_t)tok * 128 + c]     = __float2bfloat16((v0 - mean) * inv * g[c]     + bta[c]);
    xn2[(size_t)tok * 128 + c + 1] = __float2bfloat16((v1 - mean) * inv * g[c + 1] + bta[c + 1]);
}

// ---------------- K6: fused MLP v3 ----------------
// 128-token tile, 512 threads = 8 waves (4 row-groups x 2 col-groups).
// sH = one hidden HALF [128][256] bf16 (64KB -> 2 blocks/CU). fc1 writes are
// wave-private (no barrier inside fc1); 3 barriers total per block.
__global__ __launch_bounds__(512) void k_mlp3(const short* __restrict__ A,
                                              const short* __restrict__ W1,
                                              const short* __restrict__ W2,
                                              const float* __restrict__ b1,
                                              const float* __restrict__ b2,
                                              const float* __restrict__ res,
                                              float* __restrict__ out) {
    __shared__ __align__(16) short sH[128 * 256];
    int t = threadIdx.x, lane = t & 63, wid = t >> 6;
    int wr = wid >> 1, wc = wid & 1;        // 4 x 2
    int m0 = blockIdx.x * 128;

    // A-frags (K=128) in registers, read once: rows wr*32 + mf*16 + (lane&15)
    short8 af[2][4];
    #pragma unroll
    for (int mf = 0; mf < 2; ++mf) {
        size_t row = m0 + wr * 32 + mf * 16 + (lane & 15);
        #pragma unroll
        for (int kk = 0; kk < 4; ++kk)
            af[mf][kk] = *reinterpret_cast<const short8*>(A + row * 128 + (kk * 4 + (lane >> 4)) * 8);
    }

    float4v acc2[2][4];
    #pragma unroll
    for (int mf = 0; mf < 2; ++mf)
        #pragma unroll
        for (int nf = 0; nf < 4; ++nf) acc2[mf][nf] = (float4v){0.f, 0.f, 0.f, 0.f};

    for (int half = 0; half < 2; ++half) {
        if (half) __syncthreads();          // previous fc2 done reading sH
        // ---- fc1 for this half: hidden cols half*256 + hcl*128 + wc*64 + [0,64) ----
        #pragma unroll
        for (int hcl = 0; hcl < 2; ++hcl) {
            int hbase = half * 256 + hcl * 128 + wc * 64;    // global hidden base
            float4v acc1[2][4];
            #pragma unroll
            for (int mf = 0; mf < 2; ++mf)
                #pragma unroll
                for (int nf = 0; nf < 4; ++nf) acc1[mf][nf] = (float4v){0.f, 0.f, 0.f, 0.f};
            #pragma unroll
            for (int kk = 0; kk < 4; ++kk) {
                int crb = kk * 4 + (lane >> 4);
                short8 bfr[4];
                #pragma unroll
                for (int nf = 0; nf < 4; ++nf) {
                    int hrow = hbase + nf * 16 + (lane & 15);
                    bfr[nf] = *reinterpret_cast<const short8*>(W1 + (size_t)hrow * 128 + crb * 8);
                }
                #pragma unroll
                for (int mf = 0; mf < 2; ++mf)
                    #pragma unroll
                    for (int nf = 0; nf < 4; ++nf)
                        acc1[mf][nf] = mfma16(af[mf][kk], bfr[nf], acc1[mf][nf]);
            }
            // gelu -> sH (wave-private rows x cols; swizzled chunks; no barrier)
            #pragma unroll
            for (int nf = 0; nf < 4; ++nf) {
                int hcol = hcl * 128 + wc * 64 + nf * 16 + (lane & 15);  // [0,256) within half
                float b1v = b1[half * 256 + hcol];
                int ch = hcol >> 3, e = hcol & 7;
                #pragma unroll
                for (int mf = 0; mf < 2; ++mf) {
                    #pragma unroll
                    for (int r = 0; r < 4; ++r) {
                        int row = wr * 32 + mf * 16 + (lane >> 4) * 4 + r;
                        float vv = acc1[mf][nf][r] + b1v;
                        vv = 0.5f * vv * (1.0f + erff(vv * 0.7071067811865475f));
                        sH[row * 256 + (ch ^ (row & 7)) * 8 + e] = f2bs(vv);
                    }
                }
            }
        }
        __syncthreads();                    // sH half complete
        // ---- fc2 partial: acc2 += sH(128x256) @ W2[:, half*256:+256]^T ----
        #pragma unroll
        for (int kk2 = 0; kk2 < 8; ++kk2) {
            int cr = kk2 * 4 + (lane >> 4);     // logical chunk within half [0,32)
            short8 hf[2], bfr[4];
            #pragma unroll
            for (int mf = 0; mf < 2; ++mf) {
                int row = wr * 32 + mf * 16 + (lane & 15);
                hf[mf] = *reinterpret_cast<const short8*>(&sH[row * 256 + (cr ^ (row & 7)) * 8]);
            }
            #pragma unroll
            for (int nf = 0; nf < 4; ++nf) {
                int o = wc * 64 + nf * 16 + (lane & 15);
                bfr[nf] = *reinterpret_cast<const short8*>(W2 + (size_t)o * 512 + half * 256 + cr * 8);
            }
            #pragma unroll
            for (int mf = 0; mf < 2; ++mf)
                #pragma unroll
                for (int nf = 0; nf < 4; ++nf)
                    acc2[mf][nf] = mfma16(hf[mf], bfr[nf], acc2[mf][nf]);
        }
    }

    // ---- epilogue: + b2 + residual -> fp32 out ----
    #pragma unroll
    for (int nf = 0; nf < 4; ++nf) {
        int o = wc * 64 + nf * 16 + (lane & 15);
        float b2v = b2[o];
        #pragma unroll
        for (int mf = 0; mf < 2; ++mf) {
            #pragma unroll
            for (int r = 0; r < 4; ++r) {
                size_t row = m0 + wr * 32 + mf * 16 + (lane >> 4) * 4 + r;
                out[row * 128 + o] = acc2[mf][nf][r] + b2v + res[row * 128 + o];
            }
        }
    }
}

extern "C" void kernel_launch(void* const* d_in, const int* in_sizes, int n_in,
                              void* d_out, int out_size, void* d_ws, size_t ws_size,
                              hipStream_t stream) {
    const float* x      = (const float*)d_in[0];
    const float* mask   = (const float*)d_in[1];
    const int*   relidx = (const int*)  d_in[2];
    const float* n1g    = (const float*)d_in[3];
    const float* n1b    = (const float*)d_in[4];
    const float* qkv_w  = (const float*)d_in[5];
    const float* qkv_b  = (const float*)d_in[6];
    const float* rpb    = (const float*)d_in[7];
    const float* proj_w = (const float*)d_in[8];
    const float* proj_b = (const float*)d_in[9];
    const float* n2g    = (const float*)d_in[10];
    const float* n2b    = (const float*)d_in[11];
    const float* fc1_w  = (const float*)d_in[12];
    const float* fc1_b  = (const float*)d_in[13];
    const float* fc2_w  = (const float*)d_in[14];
    const float* fc2_b  = (const float*)d_in[15];

    char* ws = (char*)d_ws;
    const size_t MB = 1024 * 1024;
    bf16*  xw   = (bf16*)(ws);                // [0, 24.5)    k1 -> qkvG
    bf16*  qkv  = (bf16*)(ws + 25 * MB);      // [25, 98.5)   qkvG -> attn
    bf16*  aout = (bf16*)(ws + 99 * MB);      // [99, 123.5)  attn -> projG
    bf16*  ptmp = (bf16*)(ws + 124 * MB);     // [124, 148.5) projG -> resid_ln2
    short* cmbT = (short*)(ws + 149 * MB);    // [149, 173.5) cmb -> attn
    float* x1   = (float*)(ws);               // [0, 49)      resid_ln2 -> mlp
    bf16*  xn2  = (bf16*)(ws + 50 * MB);      // [50, 74.5)   resid_ln2 -> mlp
    short* wbf  = (short*)(ws + 174 * MB);    // [174, 174.4) whole launch
    float* out  = (float*)d_out;

    const short* wq = wbf;
    const short* wp = wbf + 49152;
    const short* w1 = wbf + 65536;
    const short* w2 = wbf + 131072;

    k_wconv<<<768, 256, 0, stream>>>(qkv_w, proj_w, fc1_w, fc2_w, wbf);
    k_cmb<<<dim3(49, 1024), 256, 0, stream>>>(relidx, rpb, mask, cmbT);
    k_ln1_win<<<NTOK / 4, 256, 0, stream>>>(x, n1g, n1b, xw);
    k_gemm_mfma<128, 0><<<dim3(NTOK / 128, 3), 256, 0, stream>>>((const short*)xw, wq, qkv_b, qkv, 384);
    k_attn_mfma<<<BNc * 4, 256, 0, stream>>>(qkv, cmbT, aout);
    k_gemm_mfma<128, 1><<<dim3(NTOK / 128, 1), 256, 0, stream>>>((const short*)aout, wp, proj_b, ptmp, 128);
    k_resid_ln2<<<NTOK / 4, 256, 0, stream>>>(x, ptmp, n2g, n2b, x1, xn2);
    k_mlp3<<<NTOK / 128, 512, 0, stream>>>((const short*)xn2, w1, w2, fc1_b, fc2_b, x1, out);
}

// Round 10
// 280.145 us; speedup vs baseline: 1.2940x; 1.2940x over previous
//
#include <hip/hip_runtime.h>
#include <hip/hip_bf16.h>
#include <math.h>

using bf16 = __hip_bfloat16;
typedef __attribute__((ext_vector_type(8))) short short8;
typedef __attribute__((ext_vector_type(4))) float float4v;
typedef __attribute__((ext_vector_type(4))) unsigned short ushort4v;

#define DEVI __device__ __forceinline__

constexpr int Nc = 98;
constexpr int NWIN = 256;
constexpr int BNc = 4 * NWIN;           // 1024 windows
constexpr int NTOK = 4 * 8 * 56 * 56;   // 100352 tokens

DEVI float b2f(bf16 v) { return __bfloat162float(v); }
DEVI short f2bs(float v) { bf16 h = __float2bfloat16(v); return *reinterpret_cast<short*>(&h); }

DEVI float4v mfma16(short8 a, short8 b, float4v c) {
    return __builtin_amdgcn_mfma_f32_16x16x32_bf16(a, b, c, 0, 0, 0);
}

// async global->LDS, 16B per lane; LDS dest is wave-uniform base + lane*16
DEVI void gload16(const short* g, short* lds_base) {
    __builtin_amdgcn_global_load_lds((const __attribute__((address_space(1))) unsigned int*)g,
                                     (__attribute__((address_space(3))) unsigned int*)lds_base,
                                     16, 0, 0);
}

// ---------------- K0a: weights fp32 -> bf16 (qkv|proj|fc1|fc2 packed) ----------------
__global__ __launch_bounds__(256) void k_wconv(const float* __restrict__ qw, const float* __restrict__ pw,
                                               const float* __restrict__ f1, const float* __restrict__ f2,
                                               short* __restrict__ wbf) {
    int i = blockIdx.x * 256 + threadIdx.x;           // 196608 total
    float v;
    if (i < 49152) v = qw[i];
    else if (i < 65536) v = pw[i - 49152];
    else if (i < 131072) v = f1[i - 65536];
    else v = f2[i - 131072];
    wbf[i] = f2bs(v);
}

// ---------------- K0b: combined bias+mask table, transposed ----------------
__global__ __launch_bounds__(256) void k_cmb(const int* __restrict__ relidx, const float* __restrict__ rpb,
                                             const float* __restrict__ mask, short* __restrict__ cmbT) {
    int elem = blockIdx.x * 256 + threadIdx.x;        // [0,12544)
    int sl = blockIdx.y;                              // wc*4+head
    int wc = sl >> 2, head = sl & 3;
    int j = elem / 112, i = elem - j * 112;
    float v;
    if (j >= 98)      v = -1e30f;
    else if (i >= 98) v = 0.f;
    else              v = rpb[relidx[i * 98 + j] * 4 + head] + mask[(size_t)wc * 9604 + i * 98 + j];
    cmbT[(size_t)sl * 12544 + elem] = f2bs(v);
}

// ---------------- K1: LN1 + cyclic shift + window partition ----------------
__global__ __launch_bounds__(256) void k_ln1_win(const float* __restrict__ x,
                                                 const float* __restrict__ g,
                                                 const float* __restrict__ bta,
                                                 bf16* __restrict__ xw) {
    int wave = (blockIdx.x * 256 + threadIdx.x) >> 6;
    int lane = threadIdx.x & 63;
    int win = wave / Nc, n = wave % Nc;
    int bb = win >> 8;
    int rem = win & 255;
    int dblk = rem >> 6, hblk = (rem >> 3) & 7, wblk = rem & 7;
    int wd = n / 49, r49 = n % 49, wh = r49 / 7, ww = r49 % 7;
    int d = dblk * 2 + wd, h = hblk * 7 + wh, w = wblk * 7 + ww;
    int ds = d + 1;  if (ds >= 8)  ds -= 8;
    int hs = h + 3;  if (hs >= 56) hs -= 56;
    int wsp = w + 3; if (wsp >= 56) wsp -= 56;
    size_t src = ((((size_t)bb * 8 + ds) * 56 + hs) * 56 + wsp) * 128;
    int c = lane * 2;
    float2 v = *reinterpret_cast<const float2*>(x + src + c);
    float v0 = v.x, v1 = v.y;
    float s = v0 + v1, sq = v0 * v0 + v1 * v1;
    #pragma unroll
    for (int off = 32; off; off >>= 1) { s += __shfl_xor(s, off); sq += __shfl_xor(sq, off); }
    float mean = s * (1.0f / 128.0f);
    float var  = sq * (1.0f / 128.0f) - mean * mean;
    float inv  = rsqrtf(var + 1e-5f);
    size_t dst = (size_t)wave * 128 + c;
    xw[dst]     = __float2bfloat16((v0 - mean) * inv * g[c]     + bta[c]);
    xw[dst + 1] = __float2bfloat16((v1 - mean) * inv * g[c + 1] + bta[c + 1]);
}

// ---------------- MFMA GEMM: out[M,N] = A[M,K](bf16) @ W[N,K](bf16)^T + bias ----------------
// Staging via global_load_lds (linear LDS dest, pre-swizzled global source; involution ch^=row&7).
// EPI: 0 = qkv (scale cols<128), 1 = plain, 2 = exact gelu, 3 = +residual (fp32 out)
template<int K, int EPI, typename OutT>
__global__ __launch_bounds__(256) void k_gemm_mfma(const short* __restrict__ A,
                                                   const short* __restrict__ Bw,
                                                   const float* __restrict__ bias,
                                                   const float* __restrict__ res,
                                                   OutT* __restrict__ out, int Ncols) {
    __shared__ __align__(16) short smem[128 * 136];   // staging (2x8192) U bf16-epilogue (17408)
    short* sA = smem;
    short* sB = smem + 8192;
    int t = threadIdx.x;
    int lane = t & 63, wid = t >> 6;
    int wm = wid >> 1, wn = wid & 1;
    int rsub = lane >> 3;                  // row within 8-row group
    int csl  = lane & 7;                   // physical chunk slot
    int m0 = blockIdx.x * 128, n0 = blockIdx.y * 128;
    float4v acc[4][4];
    #pragma unroll
    for (int a = 0; a < 4; ++a)
        #pragma unroll
        for (int b = 0; b < 4; ++b) acc[a][b] = (float4v){0.f, 0.f, 0.f, 0.f};

    for (int k0 = 0; k0 < K; k0 += 64) {
        // each wave issues 4 A + 4 B global_load_lds (1KB each, covers 8 rows of 64 cols)
        #pragma unroll
        for (int v = 0; v < 4; ++v) {
            int row = (wid * 4 + v) * 8 + rsub;             // 0..127
            int ch = csl ^ (row & 7);                       // inverse-swizzled source chunk
            gload16(A + (size_t)(m0 + row) * K + k0 + ch * 8, sA + (wid * 4 + v) * 512);
            gload16(Bw + (size_t)(n0 + row) * K + k0 + ch * 8, sB + (wid * 4 + v) * 512);
        }
        __syncthreads();
        #pragma unroll
        for (int kk = 0; kk < 2; ++kk) {
            int crb = kk * 4 + (lane >> 4);
            short8 af[4], bfr[4];
            #pragma unroll
            for (int mf = 0; mf < 4; ++mf) {
                int row = wm * 64 + mf * 16 + (lane & 15);
                af[mf] = *reinterpret_cast<const short8*>(&sA[row * 64 + (crb ^ (row & 7)) * 8]);
            }
            #pragma unroll
            for (int nf = 0; nf < 4; ++nf) {
                int row = wn * 64 + nf * 16 + (lane & 15);
                bfr[nf] = *reinterpret_cast<const short8*>(&sB[row * 64 + (crb ^ (row & 7)) * 8]);
            }
            #pragma unroll
            for (int mf = 0; mf < 4; ++mf)
                #pragma unroll
                for (int nf = 0; nf < 4; ++nf)
                    acc[mf][nf] = mfma16(af[mf], bfr[nf], acc[mf][nf]);
        }
        __syncthreads();
    }
    if constexpr (sizeof(OutT) == 2) {
        // ---- bf16 epilogue: acc -> LDS [128][136] -> 16B global stores ----
        #pragma unroll
        for (int nf = 0; nf < 4; ++nf) {
            int col = wn * 64 + nf * 16 + (lane & 15);
            int gcol = n0 + col;
            float bv = bias[gcol];
            #pragma unroll
            for (int mf = 0; mf < 4; ++mf) {
                #pragma unroll
                for (int r = 0; r < 4; ++r) {
                    int row = wm * 64 + mf * 16 + (lane >> 4) * 4 + r;
                    float v = acc[mf][nf][r] + bv;
                    if (EPI == 0) { if (gcol < 128) v *= 0.17677669529663689f; }
                    else if (EPI == 2) { v = 0.5f * v * (1.0f + erff(v * 0.7071067811865475f)); }
                    smem[row * 136 + col] = f2bs(v);
                }
            }
        }
        __syncthreads();
        #pragma unroll
        for (int p = 0; p < 8; ++p) {
            int row = p * 16 + (t >> 4);
            int c0 = (t & 15) * 8;
            uint4 val = *reinterpret_cast<const uint4*>(&smem[row * 136 + c0]);
            *reinterpret_cast<uint4*>(out + (size_t)(m0 + row) * Ncols + n0 + c0) = val;
        }
    } else {
        // ---- fp32 epilogue (EPI==3): + bias + residual, direct stores ----
        #pragma unroll
        for (int mf = 0; mf < 4; ++mf) {
            #pragma unroll
            for (int nf = 0; nf < 4; ++nf) {
                int col = n0 + wn * 64 + nf * 16 + (lane & 15);
                float bv = bias[col];
                #pragma unroll
                for (int r = 0; r < 4; ++r) {
                    size_t row = m0 + wm * 64 + mf * 16 + (lane >> 4) * 4 + r;
                    float v = acc[mf][nf][r] + bv;
                    if (EPI == 3) v += res[row * 128 + col];
                    out[row * Ncols + col] = v;
                }
            }
        }
    }
}

// ---------------- K3: MFMA window attention ----------------
__global__ __launch_bounds__(256, 4) void k_attn_mfma(const bf16* __restrict__ qkv,
                                                      const short* __restrict__ cmbT,
                                                      bf16* __restrict__ aout) {
    constexpr int QP = 40;
    constexpr int VP = 136;
    constexpr int PP = 136;
    __shared__ __align__(16) char smem[8704 + 30464];
    short* sVT = (short*)smem;                     // [32][136]
    short* sQ  = (short*)(smem + 8704);            // [112][40]
    short* sK  = (short*)(smem + 8704 + 8960);     // [112][40]
    short* sP  = (short*)(smem + 8704);            // [112][136]  (aliases sQ/sK)
    int t = threadIdx.x, lane = t & 63, wid = t >> 6;
    int win = blockIdx.x >> 2, head = blockIdx.x & 3;
    const bf16* base = qkv + (size_t)win * Nc * 384 + head * 32;

    for (int idx = t; idx < Nc * 4; idx += 256) {
        int i = idx >> 2, g = idx & 3;
        uint4 q4 = *reinterpret_cast<const uint4*>(base + (size_t)i * 384 + g * 8);
        uint4 k4 = *reinterpret_cast<const uint4*>(base + (size_t)i * 384 + 128 + g * 8);
        uint4 v4 = *reinterpret_cast<const uint4*>(base + (size_t)i * 384 + 256 + g * 8);
        *reinterpret_cast<uint4*>(&sQ[i * QP + g * 8]) = q4;
        *reinterpret_cast<uint4*>(&sK[i * QP + g * 8]) = k4;
        const short* vp = reinterpret_cast<const short*>(&v4);
        #pragma unroll
        for (int e = 0; e < 8; ++e) sVT[(g * 8 + e) * VP + i] = vp[e];
    }
    for (int idx = t; idx < 14 * QP; idx += 256) {
        int r = 98 + idx / QP, c = idx % QP;
        sQ[r * QP + c] = 0; sK[r * QP + c] = 0;
    }
    for (int idx = t; idx < 32 * 30; idx += 256) {
        int d = idx / 30, c = 98 + idx % 30;
        sVT[d * VP + c] = 0;
    }
    __syncthreads();

    float4v s[2][7];
    #pragma unroll
    for (int mi = 0; mi < 2; ++mi)
        #pragma unroll
        for (int fn = 0; fn < 7; ++fn) s[mi][fn] = (float4v){0.f, 0.f, 0.f, 0.f};
    short8 qf[2];
    #pragma unroll
    for (int mi = 0; mi < 2; ++mi) {
        if (wid * 2 + mi < 7) {
            int row = (wid * 2 + mi) * 16 + (lane & 15);
            qf[mi] = *reinterpret_cast<const short8*>(&sQ[row * QP + (lane >> 4) * 8]);
        }
    }
    #pragma unroll
    for (int fn = 0; fn < 7; ++fn) {
        short8 kf = *reinterpret_cast<const short8*>(&sK[(fn * 16 + (lane & 15)) * QP + (lane >> 4) * 8]);
        #pragma unroll
        for (int mi = 0; mi < 2; ++mi) {
            if (wid * 2 + mi < 7) s[mi][fn] = mfma16(qf[mi], kf, s[mi][fn]);
        }
    }

    const unsigned short* cb = (const unsigned short*)(cmbT + (size_t)((win & 255) * 4 + head) * 12544);
    #pragma unroll
    for (int mi = 0; mi < 2; ++mi) {
        if (wid * 2 + mi >= 7) continue;
        int i0 = (wid * 2 + mi) * 16 + (lane >> 4) * 4;
        #pragma unroll
        for (int fn = 0; fn < 7; ++fn) {
            int j = fn * 16 + (lane & 15);
            ushort4v bm4 = *reinterpret_cast<const ushort4v*>(cb + j * 112 + i0);
            #pragma unroll
            for (int r = 0; r < 4; ++r) {
                union { unsigned u; float f; } cv; cv.u = ((unsigned)bm4[r]) << 16;
                s[mi][fn][r] = __expf(s[mi][fn][r] + cv.f);
            }
        }
        #pragma unroll
        for (int r = 0; r < 4; ++r) {
            float sum = 0.f;
            #pragma unroll
            for (int fn = 0; fn < 7; ++fn) sum += s[mi][fn][r];
            #pragma unroll
            for (int m = 1; m <= 8; m <<= 1) sum += __shfl_xor(sum, m);
            float inv = 1.0f / sum;
            #pragma unroll
            for (int fn = 0; fn < 7; ++fn) s[mi][fn][r] *= inv;
        }
    }
    __syncthreads();

    for (int idx = t; idx < 112 * 16; idx += 256) {
        int rr = idx >> 4, c2 = 112 + (idx & 15);
        sP[rr * PP + c2] = 0;
    }
    #pragma unroll
    for (int mi = 0; mi < 2; ++mi) {
        if (wid * 2 + mi >= 7) continue;
        int i0 = (wid * 2 + mi) * 16 + (lane >> 4) * 4;
        #pragma unroll
        for (int r = 0; r < 4; ++r) {
            #pragma unroll
            for (int fn = 0; fn < 7; ++fn) {
                int j = fn * 16 + (lane & 15);
                sP[(i0 + r) * PP + j] = f2bs(s[mi][fn][r]);
            }
        }
    }
    __syncthreads();

    float4v o[2][2];
    #pragma unroll
    for (int mi = 0; mi < 2; ++mi)
        #pragma unroll
        for (int nd = 0; nd < 2; ++nd) o[mi][nd] = (float4v){0.f, 0.f, 0.f, 0.f};
    #pragma unroll
    for (int jc = 0; jc < 4; ++jc) {
        short8 pf[2];
        #pragma unroll
        for (int mi = 0; mi < 2; ++mi) {
            if (wid * 2 + mi < 7) {
                int row = (wid * 2 + mi) * 16 + (lane & 15);
                pf[mi] = *reinterpret_cast<const short8*>(&sP[row * PP + jc * 32 + (lane >> 4) * 8]);
            }
        }
        #pragma unroll
        for (int nd = 0; nd < 2; ++nd) {
            short8 vf = *reinterpret_cast<const short8*>(&sVT[(nd * 16 + (lane & 15)) * VP + jc * 32 + (lane >> 4) * 8]);
            #pragma unroll
            for (int mi = 0; mi < 2; ++mi) {
                if (wid * 2 + mi < 7) o[mi][nd] = mfma16(pf[mi], vf, o[mi][nd]);
            }
        }
    }
    bf16* obase = aout + (size_t)win * Nc * 128 + head * 32;
    #pragma unroll
    for (int mi = 0; mi < 2; ++mi) {
        if (wid * 2 + mi >= 7) continue;
        #pragma unroll
        for (int nd = 0; nd < 2; ++nd) {
            int d = nd * 16 + (lane & 15);
            #pragma unroll
            for (int r = 0; r < 4; ++r) {
                int i = (wid * 2 + mi) * 16 + (lane >> 4) * 4 + r;
                if (i < 98) obase[(size_t)i * 128 + d] = __float2bfloat16(o[mi][nd][r]);
            }
        }
    }
}

// ---------------- K5: window reverse + residual + LN2 fused ----------------
__global__ __launch_bounds__(256) void k_resid_ln2(const float* __restrict__ x,
                                                   const bf16* __restrict__ pt,
                                                   const float* __restrict__ g,
                                                   const float* __restrict__ bta,
                                                   float* __restrict__ x1,
                                                   bf16* __restrict__ xn2) {
    int tok = (blockIdx.x * 256 + threadIdx.x) >> 6;
    int lane = threadIdx.x & 63;
    int ww = tok % 56; int t2 = tok / 56;
    int hh = t2 % 56;  int t3 = t2 / 56;
    int dd = t3 & 7;   int bb = t3 >> 3;
    int d = dd + 7;  if (d >= 8)  d -= 8;
    int h = hh + 53; if (h >= 56) h -= 56;
    int w = ww + 53; if (w >= 56) w -= 56;
    int win = ((bb * 4 + (d >> 1)) * 8 + h / 7) * 8 + w / 7;
    int n = (d & 1) * 49 + (h % 7) * 7 + (w % 7);
    int c = lane * 2;
    const bf16* pp = pt + ((size_t)win * Nc + n) * 128 + c;
    float2 xv = *reinterpret_cast<const float2*>(x + (size_t)tok * 128 + c);
    float v0 = xv.x + b2f(pp[0]);
    float v1 = xv.y + b2f(pp[1]);
    *reinterpret_cast<float2*>(x1 + (size_t)tok * 128 + c) = float2{v0, v1};
    float s = v0 + v1, sq = v0 * v0 + v1 * v1;
    #pragma unroll
    for (int off = 32; off; off >>= 1) { s += __shfl_xor(s, off); sq += __shfl_xor(sq, off); }
    float mean = s * (1.0f / 128.0f);
    float var  = sq * (1.0f / 128.0f) - mean * mean;
    float inv  = rsqrtf(var + 1e-5f);
    xn2[(size_t)tok * 128 + c]     = __float2bfloat16((v0 - mean) * inv * g[c]     + bta[c]);
    xn2[(size_t)tok * 128 + c + 1] = __float2bfloat16((v1 - mean) * inv * g[c + 1] + bta[c + 1]);
}

extern "C" void kernel_launch(void* const* d_in, const int* in_sizes, int n_in,
                              void* d_out, int out_size, void* d_ws, size_t ws_size,
                              hipStream_t stream) {
    const float* x      = (const float*)d_in[0];
    const float* mask   = (const float*)d_in[1];
    const int*   relidx = (const int*)  d_in[2];
    const float* n1g    = (const float*)d_in[3];
    const float* n1b    = (const float*)d_in[4];
    const float* qkv_w  = (const float*)d_in[5];
    const float* qkv_b  = (const float*)d_in[6];
    const float* rpb    = (const float*)d_in[7];
    const float* proj_w = (const float*)d_in[8];
    const float* proj_b = (const float*)d_in[9];
    const float* n2g    = (const float*)d_in[10];
    const float* n2b    = (const float*)d_in[11];
    const float* fc1_w  = (const float*)d_in[12];
    const float* fc1_b  = (const float*)d_in[13];
    const float* fc2_w  = (const float*)d_in[14];
    const float* fc2_b  = (const float*)d_in[15];

    char* ws = (char*)d_ws;
    const size_t MB = 1024 * 1024;
    bf16*  xw   = (bf16*)(ws);                // [0, 24.5)    k1 -> qkvG
    bf16*  qkv  = (bf16*)(ws + 25 * MB);      // [25, 98.5)   qkvG -> attn
    bf16*  aout = (bf16*)(ws + 99 * MB);      // [99, 123.5)  attn -> projG
    bf16*  ptmp = (bf16*)(ws + 124 * MB);     // [124, 148.5) projG -> resid_ln2
    short* cmbT = (short*)(ws + 149 * MB);    // [149, 173.5) cmb -> attn
    float* x1   = (float*)(ws);               // [0, 49)      resid_ln2 -> fc2
    bf16*  xn2  = (bf16*)(ws + 50 * MB);      // [50, 74.5)   resid_ln2 -> fc1
    bf16*  h1   = (bf16*)(ws + 75 * MB);      // [75, 173)    fc1 -> fc2 (aout/ptmp/cmbT dead)
    short* wbf  = (short*)(ws + 174 * MB);    // [174, 174.4) whole launch
    float* out  = (float*)d_out;

    const short* wq = wbf;
    const short* wp = wbf + 49152;
    const short* w1 = wbf + 65536;
    const short* w2 = wbf + 131072;

    k_wconv<<<768, 256, 0, stream>>>(qkv_w, proj_w, fc1_w, fc2_w, wbf);
    k_cmb<<<dim3(49, 1024), 256, 0, stream>>>(relidx, rpb, mask, cmbT);
    k_ln1_win<<<NTOK / 4, 256, 0, stream>>>(x, n1g, n1b, xw);
    k_gemm_mfma<128, 0, bf16><<<dim3(NTOK / 128, 3), 256, 0, stream>>>((const short*)xw, wq, qkv_b, nullptr, qkv, 384);
    k_attn_mfma<<<BNc * 4, 256, 0, stream>>>(qkv, cmbT, aout);
    k_gemm_mfma<128, 1, bf16><<<dim3(NTOK / 128, 1), 256, 0, stream>>>((const short*)aout, wp, proj_b, nullptr, ptmp, 128);
    k_resid_ln2<<<NTOK / 4, 256, 0, stream>>>(x, ptmp, n2g, n2b, x1, xn2);
    k_gemm_mfma<128, 2, bf16><<<dim3(NTOK / 128, 4), 256, 0, stream>>>((const short*)xn2, w1, fc1_b, nullptr, h1, 512);
    k_gemm_mfma<512, 3, float><<<dim3(NTOK / 128, 1), 256, 0, stream>>>((const short*)h1, w2, fc2_b, x1, out, 128);
}